// Round 27
// baseline (84.402 us; speedup 1.0000x reference)
//
#include <hip/hip_runtime.h>

// Problem constants
#define KC   1024        // codebook size
#define DD   64          // code dim
#define NR   65536       // total rows (16*4096)

#define DECAY     0.99f
#define ONEM      0.01f
#define EPSV      1e-5f
#define MARGIN_W  0.008f  // >= 16x the 3-pass split-bf16 error bound (~5e-4)

// d_out layout (floats), in reference return order:
#define OFF_ZQ    0
#define OFF_LOSS  4194304
#define OFF_IDX   4194305
#define OFF_NCB   4259841
#define OFF_NECS  4325377
#define OFF_NEW   4326401

// d_ws layout (bytes):
//   [0,131072)        cbh bf16 (16x16-fragment, (half,chunk)-contiguous)
//   [131072,262144)   cbm bf16 (same permutation)
//   [262144,524288)   cbT fp32 transposed codebook [d][code]
//   [524288,655360)   idxw ushort (idx mirror for vq_sums)
//   [655360,671744)   pcnt float[4][1024]
//   [671744,1720320)  psum float[4][1024][64]

typedef float  f32x4   __attribute__((ext_vector_type(4)));
typedef short  bf16x8  __attribute__((ext_vector_type(8)));

__device__ __forceinline__ unsigned short b16(float v) {
    union { float f; unsigned u; } x; x.f = v;
    return (unsigned short)((x.u + 0x7fffu + ((x.u >> 16) & 1u)) >> 16);
}
__device__ __forceinline__ float b2f(unsigned short h) {
    union { unsigned u; float f; } x; x.u = (unsigned)h << 16;
    return x.f;
}

// async global->LDS, 16B per lane: gsrc per-lane, LDS dst wave-uniform+lane*16
__device__ __forceinline__ void gload_lds16(const void* g, void* l) {
    __builtin_amdgcn_global_load_lds(
        (const __attribute__((address_space(1))) unsigned int*)g,
        (__attribute__((address_space(3))) unsigned int*)l, 16, 0, 0);
}

// 256 blocks x 256 threads: ||c||^2 table, fragment-permuted hi/mid splits
// laid out (half, chunk)-contiguous (chunk = 16 codes of one half), and the
// fp32 transposed codebook cbT[d][code].
// 16x16x32 B frag: lane = hi2*16 + col, elem = d&7; ushort index
// pi = ((hf*32 + ch)*2 + kh)*512 + lane*8 + e  (proven layout, rounds 8-25).
__global__ void vq_prep(const float* __restrict__ cb, float* __restrict__ out,
                        unsigned short* __restrict__ cbh,
                        unsigned short* __restrict__ cbm,
                        float* __restrict__ cbT) {
    const int tid = blockIdx.x * blockDim.x + threadIdx.x;
    if (tid < 65536) {
        const int code = tid >> 6, d = tid & 63;
        const int hf   = code >> 9;            // code half
        const int loc  = code & 511;
        const int ch   = loc >> 4;             // chunk 0..31 (16 codes)
        const int col  = loc & 15;
        const int kh   = d >> 5;               // k half
        const int hi2  = (d >> 3) & 3;
        const int e    = d & 7;
        const int pi   = ((hf * 32 + ch) * 2 + kh) * 512 + (hi2 * 16 + col) * 8 + e;
        const float v = cb[tid];
        const unsigned short h = b16(v);
        cbh[pi] = h;
        cbm[pi] = b16(v - b2f(h));
        cbT[d * 1024 + code] = v;              // transposed fp32 copy
    }
    if (tid < 1024) {
        const float4* c = reinterpret_cast<const float4*>(cb + tid * 64);
        float s = 0.f;
        #pragma unroll
        for (int j = 0; j < 16; ++j) {
            const float4 v = c[j];
            s += v.x*v.x + v.y*v.y + v.z*v.z + v.w*v.w;
        }
        out[OFF_NCB + tid] = s;                // ||c_k||^2 (fp32)
    }
    if (tid == 0) out[OFF_LOSS] = 0.0f;        // SSE accumulator
}

// 512 blocks x 512 threads (8 waves). Block owns 128 rows. Wave w:
// rowgrp = w&3 (32 rows = two 16-row tiles), codehalf hf = w>>2 (512 codes).
// Round-27: round-26's zero-barrier sweep RACED -- the compiler reordered
// the chunk-(c+2) global_load_lds ABOVE chunk-c's ds_reads within the single
// scheduling region (WAR on the shared buffer; inline-asm waits don't pin
// the scheduler, only sched_barrier(0) does -- guide rule 18's class).
// Fix: sched_barrier(0) fences between MFMA/bookkeeping and staging, and
// after staging. Ordering proof: compiler's lgkmcnt wait before the MFMAs
// guarantees ds_reads COMPLETED; fence pins staging issue after that; DMA
// write lands >= L2 latency after issue. vmcnt(4) counting remains valid
// (only staging loads in flight inside the fenced loop).
__global__ __launch_bounds__(512, 2) void vq_main(const float* __restrict__ z,
                                                  const float* __restrict__ cc,
                                                  const unsigned short* __restrict__ cbh,
                                                  const unsigned short* __restrict__ cbm,
                                                  const float* __restrict__ cbT,
                                                  const float* __restrict__ cb,
                                                  unsigned short* __restrict__ idxw,
                                                  float* __restrict__ out) {
    const int t    = threadIdx.x;
    const int lane = t & 63;
    const int wid  = t >> 6;
    const int rowgrp = wid & 3;
    const int hf     = wid >> 2;
    const int rowbase = blockIdx.x * 128;

    __shared__ char  ldsB[8][8192];    // wave-private 2-buffer slices (64KB)
    __shared__ float s_cc[1024];       // ||c||^2 (4096 B)
    __shared__ float s_hd[2][128];     // per-half best dist
    __shared__ int   s_hi[2][128];     // per-half best idx
    __shared__ float s_h2[2][128];     // per-half exact second dist
    __shared__ int   s_final[128];
    __shared__ int   s_flag[128];
    __shared__ float s_cd[8][32];      // rescore candidates (batched by 32)
    __shared__ int   s_cix[8][32];
    __shared__ float s_red[8];
    __shared__ int   s_nflag;

    if (t == 0) s_nflag = 0;
    s_cc[t]       = cc[t];
    s_cc[t + 512] = cc[t + 512];

    char* myl = ldsB[wid];
    const char* srcH = (const char*)cbh + (size_t)(hf * 32) * 2048;
    const char* srcM = (const char*)cbm + (size_t)(hf * 32) * 2048;

    // Prologue: stage chunks 0,1 into bufs 0,1 (4 x 1KB loads per chunk).
    #pragma unroll
    for (int c0 = 0; c0 < 2; ++c0) {
        char* dst = myl + c0 * 4096;
        gload_lds16(srcH + c0 * 2048 +        lane * 16, dst);
        gload_lds16(srcH + c0 * 2048 + 1024 + lane * 16, dst + 1024);
        gload_lds16(srcM + c0 * 2048 +        lane * 16, dst + 2048);
        gload_lds16(srcM + c0 * 2048 + 1024 + lane * 16, dst + 3072);
    }
    __builtin_amdgcn_sched_barrier(0);   // staging precedes A-frag loads

    // --- build A fragments (hi/mid) for this wave's 2x16 rows from global ---
    // 16x16x32 A layout: row = lane&15, k = kh*32 + (lane>>4)*8 + e.
    bf16x8 a0h[2], a0m[2], a1h[2], a1m[2];
    #pragma unroll
    for (int tile = 0; tile < 2; ++tile) {
        const int ar = rowbase + rowgrp * 32 + tile * 16 + (lane & 15);
        const int kb = (lane >> 4) * 8;
        const float* zr = z + (size_t)ar * 64 + kb;
        const float4 v0a = *reinterpret_cast<const float4*>(zr);
        const float4 v0b = *reinterpret_cast<const float4*>(zr + 4);
        const float4 v1a = *reinterpret_cast<const float4*>(zr + 32);
        const float4 v1b = *reinterpret_cast<const float4*>(zr + 36);
        const float z0[8] = {v0a.x, v0a.y, v0a.z, v0a.w, v0b.x, v0b.y, v0b.z, v0b.w};
        const float z1[8] = {v1a.x, v1a.y, v1a.z, v1a.w, v1b.x, v1b.y, v1b.z, v1b.w};
        #pragma unroll
        for (int e = 0; e < 8; ++e) {
            const unsigned short h0 = b16(z0[e]);
            a0h[tile][e] = (short)h0;
            a0m[tile][e] = (short)b16(z0[e] - b2f(h0));
            const unsigned short h1 = b16(z1[e]);
            a1h[tile][e] = (short)h1;
            a1m[tile][e] = (short)b16(z1[e] - b2f(h1));
        }
    }
    __syncthreads();   // s_cc visible to all waves (only barrier before merge)

    // --- zero-barrier sweep: 32 chunks x 16 codes, wave-private pipeline ---
    const int lcol   = lane & 15;
    const int lane16 = lane * 16;

    float bd[2][4], b2v[2][4]; int bk[2][4];
    #pragma unroll
    for (int tile = 0; tile < 2; ++tile)
        #pragma unroll
        for (int j = 0; j < 4; ++j) {
            bd[tile][j] = 3.4e38f; b2v[tile][j] = 3.4e38f; bk[tile][j] = 0;
        }

    for (int c = 0; c < 32; ++c) {
        // chunk c's 4 loads done (chunk c+1's 4 may stay in flight)
        if (c == 31) asm volatile("s_waitcnt vmcnt(0)" ::: "memory");
        else         asm volatile("s_waitcnt vmcnt(4)" ::: "memory");
        __builtin_amdgcn_sched_barrier(0);

        const char* bp = myl + (c & 1) * 4096;
        const bf16x8 bh0 = *reinterpret_cast<const bf16x8*>(bp +        lane16);
        const bf16x8 bh1 = *reinterpret_cast<const bf16x8*>(bp + 1024 + lane16);
        const bf16x8 bm0 = *reinterpret_cast<const bf16x8*>(bp + 2048 + lane16);
        const bf16x8 bm1 = *reinterpret_cast<const bf16x8*>(bp + 3072 + lane16);

        // two row-tiles, 3 passes (hh+hm+mh), 2 k-halves = 12 MFMAs
        f32x4 p0 = {0.f,0.f,0.f,0.f};
        f32x4 p1 = {0.f,0.f,0.f,0.f};
        p0 = __builtin_amdgcn_mfma_f32_16x16x32_bf16(a0m[0], bh0, p0, 0, 0, 0);
        p1 = __builtin_amdgcn_mfma_f32_16x16x32_bf16(a0m[1], bh0, p1, 0, 0, 0);
        p0 = __builtin_amdgcn_mfma_f32_16x16x32_bf16(a0h[0], bm0, p0, 0, 0, 0);
        p1 = __builtin_amdgcn_mfma_f32_16x16x32_bf16(a0h[1], bm0, p1, 0, 0, 0);
        p0 = __builtin_amdgcn_mfma_f32_16x16x32_bf16(a0h[0], bh0, p0, 0, 0, 0);
        p1 = __builtin_amdgcn_mfma_f32_16x16x32_bf16(a0h[1], bh0, p1, 0, 0, 0);
        p0 = __builtin_amdgcn_mfma_f32_16x16x32_bf16(a1m[0], bh1, p0, 0, 0, 0);
        p1 = __builtin_amdgcn_mfma_f32_16x16x32_bf16(a1m[1], bh1, p1, 0, 0, 0);
        p0 = __builtin_amdgcn_mfma_f32_16x16x32_bf16(a1h[0], bm1, p0, 0, 0, 0);
        p1 = __builtin_amdgcn_mfma_f32_16x16x32_bf16(a1h[1], bm1, p1, 0, 0, 0);
        p0 = __builtin_amdgcn_mfma_f32_16x16x32_bf16(a1h[0], bh1, p0, 0, 0, 0);
        p1 = __builtin_amdgcn_mfma_f32_16x16x32_bf16(a1h[1], bh1, p1, 0, 0, 0);

        const int  code = hf * 512 + c * 16 + lcol;
        const float ccv = s_cc[code];
        #pragma unroll
        for (int j = 0; j < 4; ++j) {
            const float s0 = fmaf(-2.f, p0[j], ccv);
            b2v[0][j] = __builtin_amdgcn_fmed3f(bd[0][j], s0, b2v[0][j]);
            if (s0 < bd[0][j]) { bd[0][j] = s0; bk[0][j] = code; }
            const float s1 = fmaf(-2.f, p1[j], ccv);
            b2v[1][j] = __builtin_amdgcn_fmed3f(bd[1][j], s1, b2v[1][j]);
            if (s1 < bd[1][j]) { bd[1][j] = s1; bk[1][j] = code; }
        }

        // FENCE: pin staging strictly after the ds_reads/MFMAs above.
        // (Round-26 race: without this, LLVM hoisted the DMA above the
        //  ds_reads of the same buffer.)
        __builtin_amdgcn_sched_barrier(0);
        if (c + 2 < 32) {   // stage chunk c+2 into buf (c&1) ((c+2)&1 == c&1)
            char* dst = myl + (c & 1) * 4096;
            gload_lds16(srcH + (c + 2) * 2048 +        lane * 16, dst);
            gload_lds16(srcH + (c + 2) * 2048 + 1024 + lane * 16, dst + 1024);
            gload_lds16(srcM + (c + 2) * 2048 +        lane * 16, dst + 2048);
            gload_lds16(srcM + (c + 2) * 2048 + 1024 + lane * 16, dst + 3072);
        }
        __builtin_amdgcn_sched_barrier(0);
    }

    // --- cross-lane argmin over 16 code-columns (exact first-index) ---
    #pragma unroll
    for (int m = 1; m < 16; m <<= 1) {
        #pragma unroll
        for (int tile = 0; tile < 2; ++tile)
            #pragma unroll
            for (int j = 0; j < 4; ++j) {
                const float od = __shfl_xor(bd[tile][j],  m);
                const int   oi = __shfl_xor(bk[tile][j],  m);
                const float o2 = __shfl_xor(b2v[tile][j], m);
                const float nb2 = fminf(fmaxf(bd[tile][j], od), fminf(b2v[tile][j], o2));
                if (od < bd[tile][j] || (od == bd[tile][j] && oi < bk[tile][j])) {
                    bd[tile][j] = od; bk[tile][j] = oi;
                }
                b2v[tile][j] = nb2;
            }
    }
    // D row mapping (16x16): row = (lane>>4)*4 + j
    if ((lane & 15) == 0) {
        #pragma unroll
        for (int tile = 0; tile < 2; ++tile)
            #pragma unroll
            for (int j = 0; j < 4; ++j) {
                const int r = rowgrp * 32 + tile * 16 + ((lane >> 4) << 2) + j;
                s_hd[hf][r] = bd[tile][j];
                s_hi[hf][r] = bk[tile][j];
                s_h2[hf][r] = b2v[tile][j];
            }
    }
    __syncthreads();

    // --- cross-half merge (half 0 = lower codes: tiebreak first) ---
    if (t < 128) {
        const float d0 = s_hd[0][t], d1 = s_hd[1][t];
        float bb = d0; int bi = s_hi[0][t];
        if (d1 < bb) { bb = d1; bi = s_hi[1][t]; }            // strict <
        const float sec = fminf(fmaxf(d0, d1), fminf(s_h2[0][t], s_h2[1][t]));
        s_final[t] = bi;
        if (sec - bb < MARGIN_W) {
            const int p = atomicAdd(&s_nflag, 1);
            s_flag[p] = t;
        }
    }
    __syncthreads();

    // --- cooperative exact fp32 rescore (wave = 128-code slice), 32/batch ---
    const int nf = s_nflag;
    for (int fb = 0; fb < nf; fb += 32) {
        const int ne = (nf - fb < 32) ? (nf - fb) : 32;
        {
            const int cbase2 = wid * 128;
            const int c0i = cbase2 + lane, c1i = c0i + 64;
            for (int i = 0; i < ne; ++i) {
                const int r = s_flag[fb + i];
                const float* zrow = z + (size_t)(rowbase + r) * 64;  // uniform -> s_load
                float a0 = 0.f, a1 = 0.f;
                #pragma unroll 8
                for (int d = 0; d < 64; ++d) {
                    const float zd = zrow[d];
                    const float* cr = cbT + d * 1024 + cbase2 + lane; // coalesced
                    a0 = fmaf(zd, cr[0],  a0);
                    a1 = fmaf(zd, cr[64], a1);
                }
                float bd_ = fmaf(-2.f, a0, s_cc[c0i]); int bi_ = c0i;
                const float d1 = fmaf(-2.f, a1, s_cc[c1i]);
                if (d1 < bd_) { bd_ = d1; bi_ = c1i; }               // c0i < c1i
                #pragma unroll
                for (int m = 32; m >= 1; m >>= 1) {
                    const float od = __shfl_xor(bd_, m);
                    const int   oi = __shfl_xor(bi_, m);
                    if (od < bd_ || (od == bd_ && oi < bi_)) { bd_ = od; bi_ = oi; }
                }
                if (lane == 0) { s_cd[wid][i] = bd_; s_cix[wid][i] = bi_; }
            }
        }
        __syncthreads();
        if (t < ne) {                     // finalize: lex-min over 8 waves
            float bd_ = s_cd[0][t]; int bi_ = s_cix[0][t];
            #pragma unroll
            for (int w = 1; w < 8; ++w) {
                const float d = s_cd[w][t]; const int i2 = s_cix[w][t];
                if (d < bd_ || (d == bd_ && i2 < bi_)) { bd_ = d; bi_ = i2; }
            }
            s_final[s_flag[fb + t]] = bi_;
        }
        __syncthreads();
    }

    // --- indices (float out + ushort mirror for vq_sums) ---
    if (t < 128) {
        const int k2 = s_final[t];
        out[OFF_IDX + rowbase + t] = (float)k2;
        idxw[rowbase + t] = (unsigned short)k2;
    }

    // --- phase 2: z_q write + commitment SSE (z re-read coalesced, L2-hot) ---
    float sse = 0.f;
    const float4* zb4 = reinterpret_cast<const float4*>(z) + (size_t)blockIdx.x * 2048;
    float4*       qb  = reinterpret_cast<float4*>(out + OFF_ZQ) + (size_t)blockIdx.x * 2048;
    const float4* cb4 = reinterpret_cast<const float4*>(cb);
    #pragma unroll
    for (int j = 0; j < 4; ++j) {
        const int f  = t + 512 * j;
        const int r  = f >> 4;
        const int fc = f & 15;
        const int gk = s_final[r];
        const float4 zv = zb4[f];
        const float4 cv = cb4[gk * 16 + fc];
        qb[f] = cv;                      // z_q_st == z_q numerically
        const float e0 = zv.x - cv.x, e1 = zv.y - cv.y;
        const float e2 = zv.z - cv.z, e3 = zv.w - cv.w;
        sse += e0 * e0 + e1 * e1 + e2 * e2 + e3 * e3;
    }

    // wave shfl-reduce, then 8 partials in LDS
    #pragma unroll
    for (int m = 32; m >= 1; m >>= 1) sse += __shfl_xor(sse, m);
    if (lane == 0) s_red[wid] = sse;
    __syncthreads();
    if (t == 0) {
        float tot = s_red[0];
        #pragma unroll
        for (int i = 1; i < 8; ++i) tot += s_red[i];
        atomicAdd(&out[OFF_LOSS], tot);
    }
}

// 4096 blocks x 512 threads (8 waves). Block owns (code k = b>>2, row-quarter
// q = b&3); wave w scans 2048 rows as 8 steps of ushort4 idx loads
// (4 rows/lane/step, 1-deep pipeline). Partials -> d_ws psum/pcnt.
// ZERO global atomics, deterministic ascending-row order per quarter.
__global__ __launch_bounds__(512) void vq_sums(const float* __restrict__ z,
                                               const unsigned short* __restrict__ idxw,
                                               float* __restrict__ psum,
                                               float* __restrict__ pcnt) {
    const int t    = threadIdx.x;
    const int lane = t & 63;
    const int w    = t >> 6;
    const int k    = blockIdx.x >> 2;
    const int qf   = blockIdx.x & 3;
    const int base = qf * 16384 + w * 2048;

    float acc = 0.f;
    int   c   = 0;

    typedef unsigned short u16x4 __attribute__((ext_vector_type(4)));
    const u16x4* ip = reinterpret_cast<const u16x4*>(idxw + base);
    u16x4 cur = ip[lane];
    for (int s = 0; s < 8; ++s) {
        u16x4 nxt = cur;
        if (s < 7) nxt = ip[(s + 1) * 64 + lane];
        const int r0 = base + s * 256;           // lane j covers rows r0+4j..+3
        c += (cur[0] == k) + (cur[1] == k) + (cur[2] == k) + (cur[3] == k);
        unsigned long long m;
        m = __ballot(cur[0] == k);
        while (m) { const int j = __ffsll((long long)m) - 1; m &= m - 1;
                    acc += z[(size_t)(r0 + 4 * j + 0) * 64 + lane]; }
        m = __ballot(cur[1] == k);
        while (m) { const int j = __ffsll((long long)m) - 1; m &= m - 1;
                    acc += z[(size_t)(r0 + 4 * j + 1) * 64 + lane]; }
        m = __ballot(cur[2] == k);
        while (m) { const int j = __ffsll((long long)m) - 1; m &= m - 1;
                    acc += z[(size_t)(r0 + 4 * j + 2) * 64 + lane]; }
        m = __ballot(cur[3] == k);
        while (m) { const int j = __ffsll((long long)m) - 1; m &= m - 1;
                    acc += z[(size_t)(r0 + 4 * j + 3) * 64 + lane]; }
        cur = nxt;
    }

    // cross-lane count reduce
    #pragma unroll
    for (int m2 = 32; m2 >= 1; m2 >>= 1) c += __shfl_xor(c, m2);

    __shared__ float s_a[8][64];
    __shared__ int   s_c[8];
    if (lane == 0) s_c[w] = c;
    s_a[w][lane] = acc;
    __syncthreads();
    if (w == 0) {
        float s = s_a[0][lane];
        #pragma unroll
        for (int i = 1; i < 8; ++i) s += s_a[i][lane];
        psum[(size_t)qf * 65536 + k * 64 + lane] = s;
        if (lane == 0) {
            int ct = s_c[0];
            #pragma unroll
            for (int i = 1; i < 8; ++i) ct += s_c[i];
            pcnt[qf * 1024 + k] = (float)ct;
        }
    }
}

// 64 blocks x 1024 threads: merged finalize. Every block redundantly computes
// necs + n + den for all 1024 codes (combining the four row-quarter partials
// in fixed order); block b writes its 16-code slice of new_ecs and its
// 1024-element slice of new_ew/new_cb.
__global__ __launch_bounds__(1024) void vq_final(const float* __restrict__ ema_cs,
                                                 const float* __restrict__ ema_w,
                                                 const float* __restrict__ pcnt,
                                                 const float* __restrict__ psum,
                                                 float* __restrict__ out) {
    const int k = threadIdx.x;           // code 0..1023
    const int b = blockIdx.x;
    const float cnt = ((pcnt[k] + pcnt[1024 + k]) + pcnt[2048 + k]) + pcnt[3072 + k];
    const float necs = DECAY * ema_cs[k] + ONEM * cnt;

    __shared__ float s_red[1024];
    __shared__ float s_den[1024];
    s_red[k] = necs;
    __syncthreads();
    for (int off = 512; off > 0; off >>= 1) {
        if (k < off) s_red[k] += s_red[k + off];
        __syncthreads();
    }
    const float n = s_red[0];
    s_den[k] = (necs + EPSV) / (n + (float)KC * EPSV) * n;
    if (k >= b * 16 && k < (b + 1) * 16) out[OFF_NECS + k] = necs;
    __syncthreads();

    const int e = b * 1024 + k;          // this block's slice, coalesced
    const float s = ((psum[e] + psum[65536 + e]) + psum[131072 + e]) + psum[196608 + e];
    const float ew = DECAY * ema_w[e] + ONEM * s;
    out[OFF_NEW + e] = ew;               // new_ew
    out[OFF_NCB + e] = ew / s_den[e >> 6];  // new_codebook
    if (b == 0 && k == 0) out[OFF_LOSS] = 0.25f * out[OFF_LOSS] * (1.f / 4194304.f);
}

extern "C" void kernel_launch(void* const* d_in, const int* in_sizes, int n_in,
                              void* d_out, int out_size, void* d_ws, size_t ws_size,
                              hipStream_t stream) {
    const float* z   = (const float*)d_in[0];
    const float* cb  = (const float*)d_in[1];
    const float* ecs = (const float*)d_in[2];
    const float* ew  = (const float*)d_in[3];
    float* out = (float*)d_out;

    unsigned short* cbh  = (unsigned short*)d_ws;
    unsigned short* cbm  = (unsigned short*)((char*)d_ws + 131072);
    float*          cbT  = (float*)((char*)d_ws + 262144);
    unsigned short* idxw = (unsigned short*)((char*)d_ws + 524288);
    float*          pcnt = (float*)((char*)d_ws + 655360);
    float*          psum = (float*)((char*)d_ws + 671744);

    vq_prep <<<256,  256, 0, stream>>>(cb, out, cbh, cbm, cbT);
    vq_main <<<512,  512, 0, stream>>>(z, out + OFF_NCB, cbh, cbm, cbT, cb, idxw, out);
    vq_sums <<<4096, 512, 0, stream>>>(z, idxw, psum, pcnt);
    vq_final<<<64,  1024, 0, stream>>>(ecs, ew, pcnt, psum, out);
}

// Round 28
// 78.959 us; speedup vs baseline: 1.0689x; 1.0689x over previous
//
#include <hip/hip_runtime.h>

// Problem constants
#define KC   1024        // codebook size
#define DD   64          // code dim
#define NR   65536       // total rows (16*4096)

#define DECAY     0.99f
#define ONEM      0.01f
#define EPSV      1e-5f
#define MARGIN_W  0.008f  // >= 16x the 3-pass split-bf16 error bound (~5e-4)

// d_out layout (floats), in reference return order:
#define OFF_ZQ    0
#define OFF_LOSS  4194304
#define OFF_IDX   4194305
#define OFF_NCB   4259841
#define OFF_NECS  4325377
#define OFF_NEW   4326401

// d_ws layout (bytes):
//   [0,131072)        cbh bf16 (fragment-permuted)
//   [131072,262144)   cbm bf16 (fragment-permuted)
//   [262144,524288)   cbT fp32 transposed codebook [d][code]
//   [524288,655360)   idxw ushort (idx mirror for vq_sums)
//   [655360,688128)   pcnt float[8][1024]
//   [688128,2785280)  psum float[8][1024][64]

typedef float  f32x4  __attribute__((ext_vector_type(4)));
typedef short  bf16x8 __attribute__((ext_vector_type(8)));

__device__ __forceinline__ unsigned short b16(float v) {
    union { float f; unsigned u; } x; x.f = v;
    return (unsigned short)((x.u + 0x7fffu + ((x.u >> 16) & 1u)) >> 16);
}
__device__ __forceinline__ float b2f(unsigned short h) {
    union { unsigned u; float f; } x; x.u = (unsigned)h << 16;
    return x.f;
}

// async global->LDS, 16B per lane: gsrc per-lane, LDS dst wave-uniform+lane*16
__device__ __forceinline__ void gload_lds16(const void* g, void* l) {
    __builtin_amdgcn_global_load_lds(
        (const __attribute__((address_space(1))) unsigned int*)g,
        (__attribute__((address_space(3))) unsigned int*)l, 16, 0, 0);
}

// 256 blocks x 256 threads: ||c||^2 table, fragment-permuted hi/mid splits,
// and the fp32 transposed codebook cbT[d][code]. (Round-22 proven layout.)
__global__ void vq_prep(const float* __restrict__ cb, float* __restrict__ out,
                        unsigned short* __restrict__ cbh,
                        unsigned short* __restrict__ cbm,
                        float* __restrict__ cbT) {
    const int tid = blockIdx.x * blockDim.x + threadIdx.x;
    if (tid < 65536) {
        const int code = tid >> 6, d = tid & 63;
        const int g   = code >> 4, col = code & 15;
        const int kh  = d >> 5, hi2 = (d >> 3) & 3, e = d & 7;
        const int pi  = ((g * 2 + kh) * 64 + hi2 * 16 + col) * 8 + e;
        const float v = cb[tid];
        const unsigned short h = b16(v);
        cbh[pi] = h;
        cbm[pi] = b16(v - b2f(h));
        cbT[d * 1024 + code] = v;                // transposed fp32 copy
    }
    if (tid < 1024) {
        const float4* c = reinterpret_cast<const float4*>(cb + tid * 64);
        float s = 0.f;
        #pragma unroll
        for (int j = 0; j < 16; ++j) {
            const float4 v = c[j];
            s += v.x*v.x + v.y*v.y + v.z*v.z + v.w*v.w;
        }
        out[OFF_NCB + tid] = s;                  // ||c_k||^2 (fp32)
    }
    if (tid == 0) out[OFF_LOSS] = 0.0f;          // SSE accumulator
}

// 512 blocks x 512 threads (8 waves). Block owns 128 rows; wave = 16 rows,
// all waves sweep all 1024 codes from a 4-buffer LDS B-stream (round-22
// counted-vmcnt pipeline: stage c+2 while computing c; vmcnt(2)+s_barrier+
// sched_barrier per chunk -- best measured configuration, 48us).
__global__ __launch_bounds__(512, 6) void vq_main(const float* __restrict__ z,
                                                  const float* __restrict__ cc,
                                                  const unsigned short* __restrict__ cbh,
                                                  const unsigned short* __restrict__ cbm,
                                                  const float* __restrict__ cbT,
                                                  const float* __restrict__ cb,
                                                  unsigned short* __restrict__ idxw,
                                                  float* __restrict__ out) {
    const int t    = threadIdx.x;
    const int lane = t & 63;
    const int wid  = t >> 6;
    const int rowbase = blockIdx.x * 128;

    __shared__ char  ldsB[4][16384];   // 4-buffer B stream: [cbh 8KB][cbm 8KB]
    __shared__ float s_cc[1024];       // ||c||^2 (4096 B)
    __shared__ int   s_final[128];
    __shared__ int   s_flag[128];
    __shared__ float s_cd[8][32];      // rescore candidates (batched by 32)
    __shared__ int   s_cix[8][32];
    __shared__ float s_red[8];
    __shared__ int   s_nflag;

    if (t == 0) s_nflag = 0;
    s_cc[t]       = cc[t];
    s_cc[t + 512] = cc[t + 512];

    // Prologue: stage chunks 0,1 into bufs 0,1 (wave w stages 1KB cbh + 1KB cbm).
    #pragma unroll
    for (int c0 = 0; c0 < 2; ++c0) {
        const char* sh = (const char*)cbh + c0 * 8192 + wid * 1024 + lane * 16;
        const char* sm = (const char*)cbm + c0 * 8192 + wid * 1024 + lane * 16;
        gload_lds16(sh, &ldsB[c0][wid * 1024]);
        gload_lds16(sm, &ldsB[c0][8192 + wid * 1024]);
    }

    // --- build A fragments (hi/mid) for this wave's 16 rows from global ---
    bf16x8 a0h, a0m, a1h, a1m;
    {
        const int ar = rowbase + wid * 16 + (lane & 15);  // A row = lane&15
        const int kb = (lane >> 4) * 8;                   // k base = 8*(lane>>4)
        const float* zr = z + (size_t)ar * 64 + kb;
        const float4 v0a = *reinterpret_cast<const float4*>(zr);
        const float4 v0b = *reinterpret_cast<const float4*>(zr + 4);
        const float4 v1a = *reinterpret_cast<const float4*>(zr + 32);
        const float4 v1b = *reinterpret_cast<const float4*>(zr + 36);
        const float z0[8] = {v0a.x, v0a.y, v0a.z, v0a.w, v0b.x, v0b.y, v0b.z, v0b.w};
        const float z1[8] = {v1a.x, v1a.y, v1a.z, v1a.w, v1b.x, v1b.y, v1b.z, v1b.w};
        #pragma unroll
        for (int e = 0; e < 8; ++e) {
            const unsigned short h0 = b16(z0[e]);
            a0h[e] = (short)h0;
            a0m[e] = (short)b16(z0[e] - b2f(h0));
            const unsigned short h1 = b16(z1[e]);
            a1h[e] = (short)h1;
            a1m[e] = (short)b16(z1[e] - b2f(h1));
        }
    }
    // chunk-0 loads (oldest 2 of our 4) must be in LDS; chunk-1 may fly.
    asm volatile("s_waitcnt vmcnt(2)" ::: "memory");
    __builtin_amdgcn_s_barrier();
    __builtin_amdgcn_sched_barrier(0);

    // --- sweep all 1024 codes: 16 chunks x 4 groups, B from LDS 4-buf ---
    const int lcol   = lane & 15;
    const int lane16 = lane * 16;

    float bd[4], b2v[4]; int bk[4];
    #pragma unroll
    for (int j = 0; j < 4; ++j) { bd[j] = 3.4e38f; b2v[j] = 3.4e38f; bk[j] = 0; }

    for (int c = 0; c < 16; ++c) {
        if (c + 2 < 16) {   // stage chunk c+2 (lands 2 barriers from now)
            const char* sh = (const char*)cbh + (c + 2) * 8192 + wid * 1024 + lane * 16;
            const char* sm = (const char*)cbm + (c + 2) * 8192 + wid * 1024 + lane * 16;
            gload_lds16(sh, &ldsB[(c + 2) & 3][wid * 1024]);
            gload_lds16(sm, &ldsB[(c + 2) & 3][8192 + wid * 1024]);
        }
        const char* bh = ldsB[c & 3];
        const char* bm = ldsB[c & 3] + 8192;
        #pragma unroll
        for (int gl = 0; gl < 4; ++gl) {
            const bf16x8 bh0 = *reinterpret_cast<const bf16x8*>(bh + gl * 2048 + lane16);
            const bf16x8 bh1 = *reinterpret_cast<const bf16x8*>(bh + gl * 2048 + 1024 + lane16);
            const bf16x8 bm0 = *reinterpret_cast<const bf16x8*>(bm + gl * 2048 + lane16);
            const bf16x8 bm1 = *reinterpret_cast<const bf16x8*>(bm + gl * 2048 + 1024 + lane16);

            // two independent 3-deep chains (hh+hm+mh)
            f32x4 p0 = {0.f, 0.f, 0.f, 0.f};
            f32x4 p1 = {0.f, 0.f, 0.f, 0.f};
            p0 = __builtin_amdgcn_mfma_f32_16x16x32_bf16(a0m, bh0, p0, 0, 0, 0);
            p1 = __builtin_amdgcn_mfma_f32_16x16x32_bf16(a1m, bh1, p1, 0, 0, 0);
            p0 = __builtin_amdgcn_mfma_f32_16x16x32_bf16(a0h, bm0, p0, 0, 0, 0);
            p1 = __builtin_amdgcn_mfma_f32_16x16x32_bf16(a1h, bm1, p1, 0, 0, 0);
            p0 = __builtin_amdgcn_mfma_f32_16x16x32_bf16(a0h, bh0, p0, 0, 0, 0);
            p1 = __builtin_amdgcn_mfma_f32_16x16x32_bf16(a1h, bh1, p1, 0, 0, 0);

            const float ccv = s_cc[(c * 4 + gl) * 16 + lcol];
            #pragma unroll
            for (int j = 0; j < 4; ++j) {
                const float s = fmaf(-2.f, p0[j] + p1[j], ccv);
                b2v[j] = __builtin_amdgcn_fmed3f(bd[j], s, b2v[j]);  // exact 2nd-best
                if (s < bd[j]) { bd[j] = s; bk[j] = (c * 4 + gl) * 16 + lcol; }
            }
        }
        if (c < 15) {
            if (c == 14) asm volatile("s_waitcnt vmcnt(0)" ::: "memory");
            else         asm volatile("s_waitcnt vmcnt(2)" ::: "memory");
            __builtin_amdgcn_s_barrier();
            __builtin_amdgcn_sched_barrier(0);
        }
    }

    // --- cross-lane argmin over the 16 code-columns (exact first-index) ---
    #pragma unroll
    for (int m = 1; m < 16; m <<= 1) {
        #pragma unroll
        for (int j = 0; j < 4; ++j) {
            const float od = __shfl_xor(bd[j],  m);
            const int   oi = __shfl_xor(bk[j],  m);
            const float o2 = __shfl_xor(b2v[j], m);
            const float nb2 = fminf(fmaxf(bd[j], od), fminf(b2v[j], o2));
            if (od < bd[j] || (od == bd[j] && oi < bk[j])) { bd[j] = od; bk[j] = oi; }
            b2v[j] = nb2;
        }
    }
    if ((lane & 15) == 0) {
        #pragma unroll
        for (int j = 0; j < 4; ++j) {
            const int r = wid * 16 + ((lane >> 4) << 2) + j;   // D row mapping
            s_final[r] = bk[j];
            if (b2v[j] - bd[j] < MARGIN_W) {
                const int p = atomicAdd(&s_nflag, 1);
                s_flag[p] = r;
            }
        }
    }
    __syncthreads();

    // --- cooperative exact fp32 rescore (wave = 128-code slice), 32/batch ---
    const int nf = s_nflag;
    for (int fb = 0; fb < nf; fb += 32) {
        const int ne = (nf - fb < 32) ? (nf - fb) : 32;
        {
            const int cbase = wid * 128;
            const int c0i = cbase + lane, c1i = c0i + 64;
            for (int i = 0; i < ne; ++i) {
                const int r = s_flag[fb + i];
                const float* zrow = z + (size_t)(rowbase + r) * 64;  // uniform -> s_load
                float a0 = 0.f, a1 = 0.f;
                #pragma unroll 8
                for (int d = 0; d < 64; ++d) {
                    const float zd = zrow[d];
                    const float* cr = cbT + d * 1024 + cbase + lane; // coalesced
                    a0 = fmaf(zd, cr[0],  a0);
                    a1 = fmaf(zd, cr[64], a1);
                }
                float bd_ = fmaf(-2.f, a0, s_cc[c0i]); int bi_ = c0i;
                const float d1 = fmaf(-2.f, a1, s_cc[c1i]);
                if (d1 < bd_) { bd_ = d1; bi_ = c1i; }               // c0i < c1i
                #pragma unroll
                for (int m = 32; m >= 1; m >>= 1) {
                    const float od = __shfl_xor(bd_, m);
                    const int   oi = __shfl_xor(bi_, m);
                    if (od < bd_ || (od == bd_ && oi < bi_)) { bd_ = od; bi_ = oi; }
                }
                if (lane == 0) { s_cd[wid][i] = bd_; s_cix[wid][i] = bi_; }
            }
        }
        __syncthreads();
        if (t < ne) {                     // finalize: lex-min over 8 waves
            float bd_ = s_cd[0][t]; int bi_ = s_cix[0][t];
            #pragma unroll
            for (int w = 1; w < 8; ++w) {
                const float d = s_cd[w][t]; const int i2 = s_cix[w][t];
                if (d < bd_ || (d == bd_ && i2 < bi_)) { bd_ = d; bi_ = i2; }
            }
            s_final[s_flag[fb + t]] = bi_;
        }
        __syncthreads();
    }

    // --- indices (float out + ushort mirror for vq_sums) ---
    if (t < 128) {
        const int k2 = s_final[t];
        out[OFF_IDX + rowbase + t] = (float)k2;
        idxw[rowbase + t] = (unsigned short)k2;
    }

    // --- phase 2: z_q write + commitment SSE (z re-read coalesced, L2-hot) ---
    float sse = 0.f;
    const float4* zb4 = reinterpret_cast<const float4*>(z) + (size_t)blockIdx.x * 2048;
    float4*       qb  = reinterpret_cast<float4*>(out + OFF_ZQ) + (size_t)blockIdx.x * 2048;
    const float4* cb4 = reinterpret_cast<const float4*>(cb);
    #pragma unroll
    for (int j = 0; j < 4; ++j) {
        const int f  = t + 512 * j;
        const int r  = f >> 4;
        const int fc = f & 15;
        const int gk = s_final[r];
        const float4 zv = zb4[f];
        const float4 cv = cb4[gk * 16 + fc];
        qb[f] = cv;                      // z_q_st == z_q numerically
        const float e0 = zv.x - cv.x, e1 = zv.y - cv.y;
        const float e2 = zv.z - cv.z, e3 = zv.w - cv.w;
        sse += e0 * e0 + e1 * e1 + e2 * e2 + e3 * e3;
    }

    // wave shfl-reduce, then 8 partials in LDS
    #pragma unroll
    for (int m = 32; m >= 1; m >>= 1) sse += __shfl_xor(sse, m);
    if (lane == 0) s_red[wid] = sse;
    __syncthreads();
    if (t == 0) {
        float tot = s_red[0];
        #pragma unroll
        for (int i = 1; i < 8; ++i) tot += s_red[i];
        atomicAdd(&out[OFF_LOSS], tot);
    }
}

// 8192 blocks x 512 threads (8 waves). Block owns (code k = b>>3, row-eighth
// of = b&7); wave w scans 1024 rows as 4 steps of ushort4 idx loads
// (4 rows/lane/step, 1-deep pipeline). Round-28: halves the per-wave serial
// latency chain vs 4096 blocks (the lever that governed vq_sums at every
// previous split). Partials -> d_ws psum/pcnt. ZERO global atomics,
// deterministic ascending-row order per eighth.
__global__ __launch_bounds__(512) void vq_sums(const float* __restrict__ z,
                                               const unsigned short* __restrict__ idxw,
                                               float* __restrict__ psum,
                                               float* __restrict__ pcnt) {
    const int t    = threadIdx.x;
    const int lane = t & 63;
    const int w    = t >> 6;
    const int k    = blockIdx.x >> 3;
    const int of   = blockIdx.x & 7;
    const int base = of * 8192 + w * 1024;

    float acc = 0.f;
    int   c   = 0;

    typedef unsigned short u16x4 __attribute__((ext_vector_type(4)));
    const u16x4* ip = reinterpret_cast<const u16x4*>(idxw + base);
    u16x4 cur = ip[lane];
    for (int s = 0; s < 4; ++s) {
        u16x4 nxt = cur;
        if (s < 3) nxt = ip[(s + 1) * 64 + lane];
        const int r0 = base + s * 256;           // lane j covers rows r0+4j..+3
        c += (cur[0] == k) + (cur[1] == k) + (cur[2] == k) + (cur[3] == k);
        unsigned long long m;
        m = __ballot(cur[0] == k);
        while (m) { const int j = __ffsll((long long)m) - 1; m &= m - 1;
                    acc += z[(size_t)(r0 + 4 * j + 0) * 64 + lane]; }
        m = __ballot(cur[1] == k);
        while (m) { const int j = __ffsll((long long)m) - 1; m &= m - 1;
                    acc += z[(size_t)(r0 + 4 * j + 1) * 64 + lane]; }
        m = __ballot(cur[2] == k);
        while (m) { const int j = __ffsll((long long)m) - 1; m &= m - 1;
                    acc += z[(size_t)(r0 + 4 * j + 2) * 64 + lane]; }
        m = __ballot(cur[3] == k);
        while (m) { const int j = __ffsll((long long)m) - 1; m &= m - 1;
                    acc += z[(size_t)(r0 + 4 * j + 3) * 64 + lane]; }
        cur = nxt;
    }

    // cross-lane count reduce
    #pragma unroll
    for (int m2 = 32; m2 >= 1; m2 >>= 1) c += __shfl_xor(c, m2);

    __shared__ float s_a[8][64];
    __shared__ int   s_c[8];
    if (lane == 0) s_c[w] = c;
    s_a[w][lane] = acc;
    __syncthreads();
    if (w == 0) {
        float s = s_a[0][lane];
        #pragma unroll
        for (int i = 1; i < 8; ++i) s += s_a[i][lane];
        psum[(size_t)of * 65536 + k * 64 + lane] = s;
        if (lane == 0) {
            int ct = s_c[0];
            #pragma unroll
            for (int i = 1; i < 8; ++i) ct += s_c[i];
            pcnt[of * 1024 + k] = (float)ct;
        }
    }
}

// 64 blocks x 1024 threads: merged finalize. Every block redundantly computes
// necs + n + den for all 1024 codes (combining the eight row-eighth partials
// in fixed ascending order); block b writes its 16-code slice of new_ecs and
// its 1024-element slice of new_ew/new_cb.
__global__ __launch_bounds__(1024) void vq_final(const float* __restrict__ ema_cs,
                                                 const float* __restrict__ ema_w,
                                                 const float* __restrict__ pcnt,
                                                 const float* __restrict__ psum,
                                                 float* __restrict__ out) {
    const int k = threadIdx.x;           // code 0..1023
    const int b = blockIdx.x;
    float cnt = pcnt[k];
    #pragma unroll
    for (int i = 1; i < 8; ++i) cnt += pcnt[i * 1024 + k];
    const float necs = DECAY * ema_cs[k] + ONEM * cnt;

    __shared__ float s_red[1024];
    __shared__ float s_den[1024];
    s_red[k] = necs;
    __syncthreads();
    for (int off = 512; off > 0; off >>= 1) {
        if (k < off) s_red[k] += s_red[k + off];
        __syncthreads();
    }
    const float n = s_red[0];
    s_den[k] = (necs + EPSV) / (n + (float)KC * EPSV) * n;
    if (k >= b * 16 && k < (b + 1) * 16) out[OFF_NECS + k] = necs;
    __syncthreads();

    const int e = b * 1024 + k;          // this block's slice, coalesced
    float s = psum[e];
    #pragma unroll
    for (int i = 1; i < 8; ++i) s += psum[(size_t)i * 65536 + e];
    const float ew = DECAY * ema_w[e] + ONEM * s;
    out[OFF_NEW + e] = ew;               // new_ew
    out[OFF_NCB + e] = ew / s_den[e >> 6];  // new_codebook
    if (b == 0 && k == 0) out[OFF_LOSS] = 0.25f * out[OFF_LOSS] * (1.f / 4194304.f);
}

extern "C" void kernel_launch(void* const* d_in, const int* in_sizes, int n_in,
                              void* d_out, int out_size, void* d_ws, size_t ws_size,
                              hipStream_t stream) {
    const float* z   = (const float*)d_in[0];
    const float* cb  = (const float*)d_in[1];
    const float* ecs = (const float*)d_in[2];
    const float* ew  = (const float*)d_in[3];
    float* out = (float*)d_out;

    unsigned short* cbh  = (unsigned short*)d_ws;
    unsigned short* cbm  = (unsigned short*)((char*)d_ws + 131072);
    float*          cbT  = (float*)((char*)d_ws + 262144);
    unsigned short* idxw = (unsigned short*)((char*)d_ws + 524288);
    float*          pcnt = (float*)((char*)d_ws + 655360);
    float*          psum = (float*)((char*)d_ws + 688128);

    vq_prep <<<256,  256, 0, stream>>>(cb, out, cbh, cbm, cbT);
    vq_main <<<512,  512, 0, stream>>>(z, out + OFF_NCB, cbh, cbm, cbT, cb, idxw, out);
    vq_sums <<<8192, 512, 0, stream>>>(z, idxw, psum, pcnt);
    vq_final<<<64,  1024, 0, stream>>>(ecs, ew, pcnt, psum, out);
}